// Round 1
// baseline (16647.603 us; speedup 1.0000x reference)
//
#include <hip/hip_runtime.h>
#include <cstdint>
#include <cstddef>

#define F 128     // feature dim (both in and out)
#define KCH 4     // Chebyshev order

// ---------------------------------------------------------------------------
// SpMM scatter: y[row] += scale * val * x[col]   (y must be pre-initialized)
// One 32-thread group per edge; each thread handles 4 contiguous features.
// ---------------------------------------------------------------------------
__global__ __launch_bounds__(256) void spmm_atomic(
    const int* __restrict__ rows, const int* __restrict__ cols,
    const float* __restrict__ vals, const float* __restrict__ x,
    float* __restrict__ y, float scale, int nEdges)
{
    long long g = (long long)blockIdx.x * 256 + threadIdx.x;
    int e = (int)(g >> 5);
    if (e >= nEdges) return;
    int lt = (int)(g & 31);

    int r = rows[e];
    int c = cols[e];
    float v = vals[e] * scale;

    const float4 xv = *(const float4*)(x + (size_t)c * F + lt * 4);
    float* yp = y + (size_t)r * F + lt * 4;
    atomicAdd(yp + 0, v * xv.x);
    atomicAdd(yp + 1, v * xv.y);
    atomicAdd(yp + 2, v * xv.z);
    atomicAdd(yp + 3, v * xv.w);
}

// dst = -src (works in-place)
__global__ __launch_bounds__(256) void negcopy(
    const float4* __restrict__ src, float4* __restrict__ dst, int n4)
{
    int i = blockIdx.x * 256 + threadIdx.x;
    if (i < n4) {
        float4 v = src[i];
        dst[i] = make_float4(-v.x, -v.y, -v.z, -v.w);
    }
}

// ---------------------------------------------------------------------------
// out[n, o] (+)= sum_f T[n, f] * W[o, f*4 + j]   (+ bias if initWithBias)
// Block: 256 threads, 32 rows of T per block, full 128-col output.
// Thread (rsub = t>>5, lt = t&31) computes rows rsub*4..rsub*4+3,
// cols lt*4..lt*4+3 (4x4 register tile).
// LDS: wT[f][o] (64 KB) + Ts[32][128] (16 KB) -> 2 blocks/CU.
// ---------------------------------------------------------------------------
__global__ __launch_bounds__(256) void gemm_acc(
    const float* __restrict__ T, const float* __restrict__ W,
    const float* __restrict__ bias, float* __restrict__ out,
    int n, int j, int initWithBias)
{
    __shared__ float wT[F * F];   // wT[f*128 + o] = W[o, f*4 + j]
    __shared__ float Ts[32 * F];  // row-major 32 x 128 tile of T

    int t = threadIdx.x;
    int row0 = blockIdx.x * 32;

    // stage W (transposed, j-strided) into LDS
    for (int idx = t; idx < F * F; idx += 256) {
        int fo = idx >> 7;        // f
        int o  = idx & 127;       // out col
        wT[idx] = W[(size_t)o * (F * KCH) + fo * KCH + j];
    }
    // stage T tile (coalesced float4)
    for (int idx = t; idx < 32 * F / 4; idx += 256) {
        int rr = idx >> 5;        // 32 float4 per row
        int r = row0 + rr;
        float4 v = (r < n) ? ((const float4*)(T + (size_t)r * F))[idx & 31]
                           : make_float4(0.f, 0.f, 0.f, 0.f);
        ((float4*)Ts)[idx] = v;
    }
    __syncthreads();

    int lt = t & 31;
    int rsub = t >> 5;
    int c0 = lt * 4;

    float4 acc[4];
#pragma unroll
    for (int i = 0; i < 4; i++) acc[i] = make_float4(0.f, 0.f, 0.f, 0.f);

    const float4* Ts4 = (const float4*)Ts;
    const float4* wT4 = (const float4*)wT;

    for (int f0 = 0; f0 < F; f0 += 4) {
        float4 w0 = wT4[((f0 + 0) * F + c0) >> 2];
        float4 w1 = wT4[((f0 + 1) * F + c0) >> 2];
        float4 w2 = wT4[((f0 + 2) * F + c0) >> 2];
        float4 w3 = wT4[((f0 + 3) * F + c0) >> 2];
#pragma unroll
        for (int i = 0; i < 4; i++) {
            float4 a = Ts4[((rsub * 4 + i) * F + f0) >> 2];
            acc[i].x += a.x * w0.x + a.y * w1.x + a.z * w2.x + a.w * w3.x;
            acc[i].y += a.x * w0.y + a.y * w1.y + a.z * w2.y + a.w * w3.y;
            acc[i].z += a.x * w0.z + a.y * w1.z + a.z * w2.z + a.w * w3.z;
            acc[i].w += a.x * w0.w + a.y * w1.w + a.z * w2.w + a.w * w3.w;
        }
    }

    float4 bv = *(const float4*)(bias + c0);
#pragma unroll
    for (int i = 0; i < 4; i++) {
        int r = row0 + rsub * 4 + i;
        if (r >= n) continue;
        float4* op = (float4*)(out + (size_t)r * F + c0);
        float4 o;
        if (initWithBias) {
            o = make_float4(bv.x + acc[i].x, bv.y + acc[i].y,
                            bv.z + acc[i].z, bv.w + acc[i].w);
        } else {
            float4 cur = *op;
            o = make_float4(cur.x + acc[i].x, cur.y + acc[i].y,
                            cur.z + acc[i].z, cur.w + acc[i].w);
        }
        *op = o;
    }
}

extern "C" void kernel_launch(void* const* d_in, const int* in_sizes, int n_in,
                              void* d_out, int out_size, void* d_ws, size_t ws_size,
                              hipStream_t stream)
{
    const float* x    = (const float*)d_in[0];
    const int*   rows = (const int*)d_in[1];
    const int*   cols = (const int*)d_in[2];
    const float* vals = (const float*)d_in[3];
    const float* W    = (const float*)d_in[4];
    const float* bias = (const float*)d_in[5];
    // d_in[6] is k (==4), hard-coded as KCH

    int N = in_sizes[0] / F;
    int E = in_sizes[1];
    float* out = (float*)d_out;

    size_t bufElems = (size_t)N * F;
    float* A = (float*)d_ws;           // 51.2 MB
    float* B = A + bufElems;           // 51.2 MB

    int gemmBlocks = (N + 31) / 32;
    int spmmBlocks = (int)(((long long)E * 32 + 255) / 256);
    int n4 = (int)(bufElems / 4);
    int negBlocks = (n4 + 255) / 256;

    // T0 = x : out = b + x @ W0^T
    gemm_acc<<<gemmBlocks, 256, 0, stream>>>(x, W, bias, out, N, 0, 1);

    // T1 = L x  -> A
    hipMemsetAsync(A, 0, bufElems * sizeof(float), stream);
    spmm_atomic<<<spmmBlocks, 256, 0, stream>>>(rows, cols, vals, x, A, 1.0f, E);
    gemm_acc<<<gemmBlocks, 256, 0, stream>>>(A, W, bias, out, N, 1, 0);

    // T2 = 2 L T1 - T0  -> B  (init B = -x, scatter 2*L*A)
    negcopy<<<negBlocks, 256, 0, stream>>>((const float4*)x, (float4*)B, n4);
    spmm_atomic<<<spmmBlocks, 256, 0, stream>>>(rows, cols, vals, A, B, 2.0f, E);
    gemm_acc<<<gemmBlocks, 256, 0, stream>>>(B, W, bias, out, N, 2, 0);

    // T3 = 2 L T2 - T1  -> A  (init A = -A, scatter 2*L*B)
    negcopy<<<negBlocks, 256, 0, stream>>>((const float4*)A, (float4*)A, n4);
    spmm_atomic<<<spmmBlocks, 256, 0, stream>>>(rows, cols, vals, B, A, 2.0f, E);
    gemm_acc<<<gemmBlocks, 256, 0, stream>>>(A, W, bias, out, N, 3, 0);
}

// Round 2
// 1604.797 us; speedup vs baseline: 10.3736x; 10.3736x over previous
//
#include <hip/hip_runtime.h>
#include <cstdint>
#include <cstddef>

#define F 128     // feature dim (both in and out)
#define KCH 4     // Chebyshev order

// ---------------------------------------------------------------------------
// CSR build, step 1: per-row edge counts
// ---------------------------------------------------------------------------
__global__ __launch_bounds__(256) void edge_histogram(
    const int* __restrict__ rows, int* __restrict__ cnt, int nE)
{
    int e = blockIdx.x * 256 + threadIdx.x;
    if (e < nE) atomicAdd(&cnt[rows[e]], 1);
}

// ---------------------------------------------------------------------------
// CSR build, step 2: assign each row a contiguous segment via atomic cursor.
// (Segment ORDER is arbitrary — irrelevant, we only need disjoint+contiguous.)
// ---------------------------------------------------------------------------
__global__ __launch_bounds__(256) void assign_segments(
    const int* __restrict__ cnt, int* __restrict__ rowStart,
    int* __restrict__ rowCur, int* __restrict__ cursor, int n)
{
    int r = blockIdx.x * 256 + threadIdx.x;
    if (r < n) {
        int s = atomicAdd(cursor, cnt[r]);
        rowStart[r] = s;
        rowCur[r]   = s;
    }
}

// ---------------------------------------------------------------------------
// CSR build, step 3: scatter (col, val) pairs into row segments
// ---------------------------------------------------------------------------
__global__ __launch_bounds__(256) void fill_edges(
    const int* __restrict__ rows, const int* __restrict__ cols,
    const float* __restrict__ vals, int* __restrict__ rowCur,
    int2* __restrict__ edges, int nE)
{
    int e = blockIdx.x * 256 + threadIdx.x;
    if (e < nE) {
        int r = rows[e];
        int p = atomicAdd(&rowCur[r], 1);
        edges[p] = make_int2(cols[e], __float_as_int(vals[e]));
    }
}

// ---------------------------------------------------------------------------
// Gather-based SpMM with fused Chebyshev epilogue:
//   y[row, :] = scale * sum_e val_e * x[col_e, :]  + beta * prev[row, :]
// One wave64 per row; lane i holds features 2i, 2i+1 (float2).
// Each row written exactly once -> no atomics; in-place prev==y is safe.
// Edge loop unrolled x4 for 4 outstanding 512B gathers per wave.
// ---------------------------------------------------------------------------
__global__ __launch_bounds__(256) void spmm_csr(
    const int* __restrict__ rowStart, const int* __restrict__ cnt,
    const int2* __restrict__ edges, const float* __restrict__ x,
    const float* __restrict__ prev, float* __restrict__ y,
    float scale, float beta, int n)
{
    int row = blockIdx.x * 4 + (threadIdx.x >> 6);
    if (row >= n) return;
    int lane = threadIdx.x & 63;

    int s = rowStart[row];
    int c = cnt[row];
    const float2* xb = (const float2*)x;

    float2 acc = make_float2(0.f, 0.f);
    int i = 0;
    for (; i + 4 <= c; i += 4) {
        int2 e0 = edges[s + i + 0];
        int2 e1 = edges[s + i + 1];
        int2 e2 = edges[s + i + 2];
        int2 e3 = edges[s + i + 3];
        float2 x0 = xb[(size_t)e0.x * 64 + lane];
        float2 x1 = xb[(size_t)e1.x * 64 + lane];
        float2 x2 = xb[(size_t)e2.x * 64 + lane];
        float2 x3 = xb[(size_t)e3.x * 64 + lane];
        float v0 = __int_as_float(e0.y);
        float v1 = __int_as_float(e1.y);
        float v2 = __int_as_float(e2.y);
        float v3 = __int_as_float(e3.y);
        acc.x += v0 * x0.x; acc.y += v0 * x0.y;
        acc.x += v1 * x1.x; acc.y += v1 * x1.y;
        acc.x += v2 * x2.x; acc.y += v2 * x2.y;
        acc.x += v3 * x3.x; acc.y += v3 * x3.y;
    }
    for (; i < c; ++i) {
        int2 e0 = edges[s + i];
        float2 x0 = xb[(size_t)e0.x * 64 + lane];
        float v0 = __int_as_float(e0.y);
        acc.x += v0 * x0.x; acc.y += v0 * x0.y;
    }

    float2 r = make_float2(scale * acc.x, scale * acc.y);
    if (beta != 0.f) {
        float2 p = ((const float2*)prev)[(size_t)row * 64 + lane];
        r.x += beta * p.x;
        r.y += beta * p.y;
    }
    ((float2*)y)[(size_t)row * 64 + lane] = r;
}

// ---------------------------------------------------------------------------
// out[n, o] (+)= sum_f T[n, f] * W[o, f*4 + j]   (+ bias if initWithBias)
// ---------------------------------------------------------------------------
__global__ __launch_bounds__(256) void gemm_acc(
    const float* __restrict__ T, const float* __restrict__ W,
    const float* __restrict__ bias, float* __restrict__ out,
    int n, int j, int initWithBias)
{
    __shared__ float wT[F * F];   // wT[f*128 + o] = W[o, f*4 + j]
    __shared__ float Ts[32 * F];  // row-major 32 x 128 tile of T

    int t = threadIdx.x;
    int row0 = blockIdx.x * 32;

    for (int idx = t; idx < F * F; idx += 256) {
        int fo = idx >> 7;
        int o  = idx & 127;
        wT[idx] = W[(size_t)o * (F * KCH) + fo * KCH + j];
    }
    for (int idx = t; idx < 32 * F / 4; idx += 256) {
        int rr = idx >> 5;
        int r = row0 + rr;
        float4 v = (r < n) ? ((const float4*)(T + (size_t)r * F))[idx & 31]
                           : make_float4(0.f, 0.f, 0.f, 0.f);
        ((float4*)Ts)[idx] = v;
    }
    __syncthreads();

    int lt = t & 31;
    int rsub = t >> 5;
    int c0 = lt * 4;

    float4 acc[4];
#pragma unroll
    for (int i = 0; i < 4; i++) acc[i] = make_float4(0.f, 0.f, 0.f, 0.f);

    const float4* Ts4 = (const float4*)Ts;
    const float4* wT4 = (const float4*)wT;

    for (int f0 = 0; f0 < F; f0 += 4) {
        float4 w0 = wT4[((f0 + 0) * F + c0) >> 2];
        float4 w1 = wT4[((f0 + 1) * F + c0) >> 2];
        float4 w2 = wT4[((f0 + 2) * F + c0) >> 2];
        float4 w3 = wT4[((f0 + 3) * F + c0) >> 2];
#pragma unroll
        for (int i = 0; i < 4; i++) {
            float4 a = Ts4[((rsub * 4 + i) * F + f0) >> 2];
            acc[i].x += a.x * w0.x + a.y * w1.x + a.z * w2.x + a.w * w3.x;
            acc[i].y += a.x * w0.y + a.y * w1.y + a.z * w2.y + a.w * w3.y;
            acc[i].z += a.x * w0.z + a.y * w1.z + a.z * w2.z + a.w * w3.z;
            acc[i].w += a.x * w0.w + a.y * w1.w + a.z * w2.w + a.w * w3.w;
        }
    }

    float4 bv = *(const float4*)(bias + c0);
#pragma unroll
    for (int i = 0; i < 4; i++) {
        int r = row0 + rsub * 4 + i;
        if (r >= n) continue;
        float4* op = (float4*)(out + (size_t)r * F + c0);
        float4 o;
        if (initWithBias) {
            o = make_float4(bv.x + acc[i].x, bv.y + acc[i].y,
                            bv.z + acc[i].z, bv.w + acc[i].w);
        } else {
            float4 cur = *op;
            o = make_float4(cur.x + acc[i].x, cur.y + acc[i].y,
                            cur.z + acc[i].z, cur.w + acc[i].w);
        }
        *op = o;
    }
}

extern "C" void kernel_launch(void* const* d_in, const int* in_sizes, int n_in,
                              void* d_out, int out_size, void* d_ws, size_t ws_size,
                              hipStream_t stream)
{
    const float* x    = (const float*)d_in[0];
    const int*   rows = (const int*)d_in[1];
    const int*   cols = (const int*)d_in[2];
    const float* vals = (const float*)d_in[3];
    const float* W    = (const float*)d_in[4];
    const float* bias = (const float*)d_in[5];

    int N = in_sizes[0] / F;
    int E = in_sizes[1];
    float* out = (float*)d_out;

    // ---- workspace layout ----
    size_t bufElems = (size_t)N * F;             // 12.8M floats
    float* A     = (float*)d_ws;                 // 51.2 MB  (T1, then T3)
    float* B     = A + bufElems;                 // 51.2 MB  (T2)
    int2*  edges = (int2*)(B + bufElems);        // 25.6 MB  (8B-aligned: offset 102.4MB)
    int*   cnt      = (int*)(edges + E);         // N ints
    int*   cursor   = cnt + N;                   // 1 int
    int*   rowStart = cursor + 1;                // N ints
    int*   rowCur   = rowStart + N;              // N ints

    int edgeBlocks = (E + 255) / 256;
    int rowBlocks  = (N + 255) / 256;
    int gemmBlocks = (N + 31) / 32;
    int spmmBlocks = (N + 3) / 4;

    // ---- build CSR (arbitrary segment order) ----
    hipMemsetAsync(cnt, 0, (size_t)(N + 1) * sizeof(int), stream);  // cnt + cursor
    edge_histogram<<<edgeBlocks, 256, 0, stream>>>(rows, cnt, E);
    assign_segments<<<rowBlocks, 256, 0, stream>>>(cnt, rowStart, rowCur, cursor, N);
    fill_edges<<<edgeBlocks, 256, 0, stream>>>(rows, cols, vals, rowCur, edges, E);

    // ---- T0 = x : out = b + x @ W0^T ----
    gemm_acc<<<gemmBlocks, 256, 0, stream>>>(x, W, bias, out, N, 0, 1);

    // ---- T1 = L x -> A ----
    spmm_csr<<<spmmBlocks, 256, 0, stream>>>(rowStart, cnt, edges, x, nullptr, A, 1.0f, 0.0f, N);
    gemm_acc<<<gemmBlocks, 256, 0, stream>>>(A, W, bias, out, N, 1, 0);

    // ---- T2 = 2 L T1 - T0 -> B ----
    spmm_csr<<<spmmBlocks, 256, 0, stream>>>(rowStart, cnt, edges, A, x, B, 2.0f, -1.0f, N);
    gemm_acc<<<gemmBlocks, 256, 0, stream>>>(B, W, bias, out, N, 2, 0);

    // ---- T3 = 2 L T2 - T1 -> A (in-place prev read is safe: one wave per row) ----
    spmm_csr<<<spmmBlocks, 256, 0, stream>>>(rowStart, cnt, edges, B, A, A, 2.0f, -1.0f, N);
    gemm_acc<<<gemmBlocks, 256, 0, stream>>>(A, W, bias, out, N, 3, 0);
}

// Round 3
// 966.961 us; speedup vs baseline: 17.2164x; 1.6596x over previous
//
#include <hip/hip_runtime.h>
#include <hip/hip_bf16.h>
#include <cstdint>
#include <cstddef>

#define F 128       // feature dim
#define KCH 4       // Chebyshev order
#define BSH 4       // rows per bucket = 1<<BSH
typedef __attribute__((ext_vector_type(8))) short short8;
typedef __attribute__((ext_vector_type(4))) float floatx4;

static __device__ inline float bf2f(unsigned u) {            // u = bf16 in low 16
    return __builtin_bit_cast(float, u << 16);
}
static __device__ inline unsigned short f2bf(float f) {
    return __builtin_bit_cast(unsigned short, __float2bfloat16(f));
}
static __device__ inline unsigned pack2(float a, float b) {  // low = a, high = b
    return ((unsigned)f2bf(b) << 16) | (unsigned)f2bf(a);
}

// ---------------------------------------------------------------------------
// cast x (fp32) -> plane0 (bf16). thread = 4 elements.
// ---------------------------------------------------------------------------
__global__ __launch_bounds__(256) void cast_x(
    const float4* __restrict__ x, uint2* __restrict__ p0, long long n4)
{
    long long i = (long long)blockIdx.x * 256 + threadIdx.x;
    if (i < n4) {
        float4 v = x[i];
        p0[i] = make_uint2(pack2(v.x, v.y), pack2(v.z, v.w));
    }
}

// ---------------------------------------------------------------------------
// W [128][512] fp32, W[o][f*4+j]  ->  Wp [128][512] bf16, Wp[o][j*128+f]
// ---------------------------------------------------------------------------
__global__ __launch_bounds__(256) void perm_w(
    const float* __restrict__ W, unsigned short* __restrict__ Wp)
{
    int t = blockIdx.x * 256 + threadIdx.x;   // 65536 total
    int o = t >> 9, rem = t & 511;
    int j = rem >> 7, f = rem & 127;
    Wp[t] = f2bf(W[(size_t)o * 512 + f * 4 + j]);
}

// ---------------------------------------------------------------------------
// CSR build
// ---------------------------------------------------------------------------
__global__ __launch_bounds__(256) void edge_histogram(
    const int* __restrict__ rows, int* __restrict__ cnt, int nE)
{
    int e = blockIdx.x * 256 + threadIdx.x;
    if (e < nE) atomicAdd(&cnt[rows[e]], 1);
}

__global__ __launch_bounds__(256) void bucket_setup(
    const int* __restrict__ cnt, int* __restrict__ cursor,
    int* __restrict__ rowStart, int* __restrict__ rowCur,
    int* __restrict__ bucketStart, int* __restrict__ bucketCur,
    int n, int nb)
{
    int b = blockIdx.x * 256 + threadIdx.x;
    if (b >= nb) return;
    int r0 = b << BSH;
    int sum = 0;
#pragma unroll
    for (int i = 0; i < (1 << BSH); i++) {
        int r = r0 + i;
        if (r < n) sum += cnt[r];
    }
    int start = atomicAdd(cursor, sum);
    bucketStart[b] = start;
    bucketCur[b]   = start;
    int run = start;
#pragma unroll
    for (int i = 0; i < (1 << BSH); i++) {
        int r = r0 + i;
        if (r < n) { rowStart[r] = run; rowCur[r] = run; run += cnt[r]; }
    }
}

// phase A: scatter (col,val,row) into bucket region (L2-hot window)
__global__ __launch_bounds__(256) void fill_bucket(
    const int* __restrict__ rows, const int* __restrict__ cols,
    const float* __restrict__ vals, int* __restrict__ bucketCur,
    int4* __restrict__ tmp, int nE)
{
    int e = blockIdx.x * 256 + threadIdx.x;
    if (e < nE) {
        int r = rows[e];
        int p = atomicAdd(&bucketCur[r >> BSH], 1);
        tmp[p] = make_int4(cols[e], __float_as_int(vals[e]), r, 0);
    }
}

// phase B: within-bucket re-scatter to exact row slots (reads+writes L2-hot)
__global__ __launch_bounds__(256) void fill_rows(
    const int4* __restrict__ tmp, const int* __restrict__ bucketStart,
    const int* __restrict__ bucketCur, int* __restrict__ rowCur,
    int2* __restrict__ edges)
{
    int b = blockIdx.x;
    int s = bucketStart[b];
    int e = bucketCur[b];           // == start + count after phase A
    for (int i = s + threadIdx.x; i < e; i += 256) {
        int4 t = tmp[i];
        int p = atomicAdd(&rowCur[t.z], 1);
        edges[p] = make_int2(t.x, t.y);
    }
}

// ---------------------------------------------------------------------------
// bf16 gather SpMM + fused Chebyshev epilogue:
//   y[row,:] = bf16( scale * sum_e val_e * x[col_e,:] + beta * prev[row,:] )
// wave64 per row; group g=lane>>4 handles edges i+g, i+4+g; lane l=lane&15
// loads bf16x8 (16B). fp32 accum; cross-group reduce via shfl_xor(16,32).
// ---------------------------------------------------------------------------
__global__ __launch_bounds__(256) void spmm_bf16(
    const int* __restrict__ rowStart, const int* __restrict__ rowEnd,
    const int2* __restrict__ edges, const unsigned short* __restrict__ xb,
    const unsigned short* __restrict__ prevb, unsigned short* __restrict__ yb,
    float scale, float beta, int n)
{
    int row = blockIdx.x * 4 + (threadIdx.x >> 6);
    if (row >= n) return;
    int lane = threadIdx.x & 63;
    int g = lane >> 4, l = lane & 15;

    int s = rowStart[row];
    int c = rowEnd[row] - s;

    float acc[8];
#pragma unroll
    for (int j = 0; j < 8; j++) acc[j] = 0.f;

    for (int i = 0; i < c; i += 8) {
        int i0 = i + g, i1 = i + 4 + g;
        bool ok0 = i0 < c, ok1 = i1 < c;
        int2 e0 = edges[s + (ok0 ? i0 : 0)];
        int2 e1 = edges[s + (ok1 ? i1 : 0)];
        uint4 w0 = *(const uint4*)(xb + (size_t)e0.x * F + l * 8);
        uint4 w1 = *(const uint4*)(xb + (size_t)e1.x * F + l * 8);
        float v0 = ok0 ? __int_as_float(e0.y) : 0.f;
        float v1 = ok1 ? __int_as_float(e1.y) : 0.f;
        acc[0] += v0 * bf2f(w0.x & 0xffffu); acc[1] += v0 * bf2f(w0.x >> 16);
        acc[2] += v0 * bf2f(w0.y & 0xffffu); acc[3] += v0 * bf2f(w0.y >> 16);
        acc[4] += v0 * bf2f(w0.z & 0xffffu); acc[5] += v0 * bf2f(w0.z >> 16);
        acc[6] += v0 * bf2f(w0.w & 0xffffu); acc[7] += v0 * bf2f(w0.w >> 16);
        acc[0] += v1 * bf2f(w1.x & 0xffffu); acc[1] += v1 * bf2f(w1.x >> 16);
        acc[2] += v1 * bf2f(w1.y & 0xffffu); acc[3] += v1 * bf2f(w1.y >> 16);
        acc[4] += v1 * bf2f(w1.z & 0xffffu); acc[5] += v1 * bf2f(w1.z >> 16);
        acc[6] += v1 * bf2f(w1.w & 0xffffu); acc[7] += v1 * bf2f(w1.w >> 16);
    }

#pragma unroll
    for (int j = 0; j < 8; j++) {
        acc[j] += __shfl_xor(acc[j], 16);
        acc[j] += __shfl_xor(acc[j], 32);
    }

    if (g == 0) {
        float r[8];
#pragma unroll
        for (int j = 0; j < 8; j++) r[j] = scale * acc[j];
        if (beta != 0.f) {
            uint4 p = *(const uint4*)(prevb + (size_t)row * F + l * 8);
            r[0] += beta * bf2f(p.x & 0xffffu); r[1] += beta * bf2f(p.x >> 16);
            r[2] += beta * bf2f(p.y & 0xffffu); r[3] += beta * bf2f(p.y >> 16);
            r[4] += beta * bf2f(p.z & 0xffffu); r[5] += beta * bf2f(p.z >> 16);
            r[6] += beta * bf2f(p.w & 0xffffu); r[7] += beta * bf2f(p.w >> 16);
        }
        uint4 o;
        o.x = pack2(r[0], r[1]); o.y = pack2(r[2], r[3]);
        o.z = pack2(r[4], r[5]); o.w = pack2(r[6], r[7]);
        *(uint4*)(yb + (size_t)row * F + l * 8) = o;
    }
}

// ---------------------------------------------------------------------------
// out[100k,128] = cheb[100k,512](bf16 planes) @ Wp^T + bias, via MFMA 16x16x32.
// Block = 4 waves x 16 rows. B-frags straight from L2 (Wp = 128KB, hot).
// A frag: a[j] = A[m=lane&15][k=quad*8+j];  B frag: b[j] = Wp[n=lane&15][k...]
// C/D:   row m = quad*4+reg, col n = lane&15.
// ---------------------------------------------------------------------------
__global__ __launch_bounds__(256) void gemm_mfma(
    const unsigned short* __restrict__ Tb, const unsigned short* __restrict__ Wp,
    const float* __restrict__ bias, float* __restrict__ out, int n)
{
    int wave = threadIdx.x >> 6, lane = threadIdx.x & 63;
    int l15 = lane & 15, quad = lane >> 4;
    int m0 = blockIdx.x * 64 + wave * 16;
    int m = m0 + l15;
    int mc = m < n ? m : n - 1;
    size_t planeStride = (size_t)n * F;

    floatx4 acc[8];
#pragma unroll
    for (int nt = 0; nt < 8; nt++) acc[nt] = (floatx4){0.f, 0.f, 0.f, 0.f};

    float bv[8];
#pragma unroll
    for (int nt = 0; nt < 8; nt++) bv[nt] = bias[nt * 16 + l15];

#pragma unroll
    for (int kk = 0; kk < 16; kk++) {
        const unsigned short* ap = Tb + (size_t)(kk >> 2) * planeStride
                                 + (size_t)mc * F + (kk & 3) * 32 + quad * 8;
        short8 a = __builtin_bit_cast(short8, *(const uint4*)ap);
#pragma unroll
        for (int nt = 0; nt < 8; nt++) {
            const unsigned short* bp = Wp + ((size_t)(nt * 16 + l15) << 9)
                                     + kk * 32 + quad * 8;
            short8 b = __builtin_bit_cast(short8, *(const uint4*)bp);
            acc[nt] = __builtin_amdgcn_mfma_f32_16x16x32_bf16(a, b, acc[nt], 0, 0, 0);
        }
    }

#pragma unroll
    for (int nt = 0; nt < 8; nt++) {
        int ncol = nt * 16 + l15;
#pragma unroll
        for (int r = 0; r < 4; r++) {
            int mrow = m0 + quad * 4 + r;
            if (mrow < n) out[(size_t)mrow * F + ncol] = acc[nt][r] + bv[nt];
        }
    }
}

extern "C" void kernel_launch(void* const* d_in, const int* in_sizes, int n_in,
                              void* d_out, int out_size, void* d_ws, size_t ws_size,
                              hipStream_t stream)
{
    const float* x    = (const float*)d_in[0];
    const int*   rows = (const int*)d_in[1];
    const int*   cols = (const int*)d_in[2];
    const float* vals = (const float*)d_in[3];
    const float* W    = (const float*)d_in[4];
    const float* bias = (const float*)d_in[5];

    int N = in_sizes[0] / F;
    int E = in_sizes[1];
    int NB = (N + (1 << BSH) - 1) >> BSH;
    float* out = (float*)d_out;

    // ---- workspace layout ----
    size_t planeElems = (size_t)N * F;                       // bf16 elems
    unsigned short* P0 = (unsigned short*)d_ws;              // 25.6 MB each
    unsigned short* P1 = P0 + planeElems;
    unsigned short* P2 = P1 + planeElems;
    unsigned short* P3 = P2 + planeElems;
    int2* edges = (int2*)(P3 + planeElems);                  // 25.6 MB
    unsigned short* Wp = (unsigned short*)(edges + E);       // 128 KB
    int* cnt         = (int*)(Wp + 128 * 512);               // N
    int* cursor      = cnt + N;                              // 1   (memset with cnt)
    int* rowStart    = cursor + 1;                           // N
    int* rowCur      = rowStart + N;                         // N
    int* bucketStart = rowCur + N;                           // NB
    int* bucketCur   = bucketStart + NB;                     // NB
    int4* tmp = (int4*)P2;  // 51.2 MB staging, consumed before P2/P3 written

    int edgeBlocks = (E + 255) / 256;
    long long n4 = planeElems / 4;
    int castBlocks = (int)((n4 + 255) / 256);

    // ---- independent prep ----
    cast_x<<<castBlocks, 256, 0, stream>>>((const float4*)x, (uint2*)P0, n4);
    perm_w<<<256, 256, 0, stream>>>(W, Wp);

    // ---- CSR build (two-phase, L2-localized scatter) ----
    hipMemsetAsync(cnt, 0, (size_t)(N + 1) * sizeof(int), stream);
    edge_histogram<<<edgeBlocks, 256, 0, stream>>>(rows, cnt, E);
    bucket_setup<<<(NB + 255) / 256, 256, 0, stream>>>(
        cnt, cursor, rowStart, rowCur, bucketStart, bucketCur, N, NB);
    fill_bucket<<<edgeBlocks, 256, 0, stream>>>(rows, cols, vals, bucketCur, tmp, E);
    fill_rows<<<NB, 256, 0, stream>>>(tmp, bucketStart, bucketCur, rowCur, edges);

    // ---- Chebyshev recurrence (rowCur now == rowStart + cnt == rowEnd) ----
    int spmmBlocks = (N + 3) / 4;
    spmm_bf16<<<spmmBlocks, 256, 0, stream>>>(rowStart, rowCur, edges, P0, nullptr, P1, 1.0f,  0.0f, N);
    spmm_bf16<<<spmmBlocks, 256, 0, stream>>>(rowStart, rowCur, edges, P1, P0,      P2, 2.0f, -1.0f, N);
    spmm_bf16<<<spmmBlocks, 256, 0, stream>>>(rowStart, rowCur, edges, P2, P1,      P3, 2.0f, -1.0f, N);

    // ---- fused projection: out = cheb @ Wp^T + b ----
    gemm_mfma<<<(N + 63) / 64, 256, 0, stream>>>(P0, Wp, bias, out, N);
}

// Round 4
// 700.295 us; speedup vs baseline: 23.7723x; 1.3808x over previous
//
#include <hip/hip_runtime.h>
#include <hip/hip_bf16.h>
#include <cstdint>
#include <cstddef>

#define F 128       // feature dim
#define BSH 8       // rows per bucket = 256
#define MAXB 512    // max buckets supported (N <= 131072)
typedef __attribute__((ext_vector_type(8))) short short8;
typedef __attribute__((ext_vector_type(4))) float floatx4;

static __device__ inline float bf2f(unsigned u) {            // u = bf16 in low 16
    return __builtin_bit_cast(float, u << 16);
}
static __device__ inline unsigned short f2bf(float f) {
    return __builtin_bit_cast(unsigned short, __float2bfloat16(f));
}
static __device__ inline unsigned pack2(float a, float b) {  // low = a, high = b
    return ((unsigned)f2bf(b) << 16) | (unsigned)f2bf(a);
}

// ---------------------------------------------------------------------------
// cast x (fp32) -> plane0 (bf16). thread = 4 elements.
// ---------------------------------------------------------------------------
__global__ __launch_bounds__(256) void cast_x(
    const float4* __restrict__ x, uint2* __restrict__ p0, long long n4)
{
    long long i = (long long)blockIdx.x * 256 + threadIdx.x;
    if (i < n4) {
        float4 v = x[i];
        p0[i] = make_uint2(pack2(v.x, v.y), pack2(v.z, v.w));
    }
}

// ---------------------------------------------------------------------------
// W [128][512] fp32, W[o][f*4+j]  ->  Wp [128][512] bf16, Wp[o][j*128+f]
// ---------------------------------------------------------------------------
__global__ __launch_bounds__(256) void perm_w(
    const float* __restrict__ W, unsigned short* __restrict__ Wp)
{
    int t = blockIdx.x * 256 + threadIdx.x;   // 65536 total
    int o = t >> 9, rem = t & 511;
    int j = rem >> 7, f = rem & 127;
    Wp[t] = f2bf(W[(size_t)o * 512 + f * 4 + j]);
}

// ---------------------------------------------------------------------------
// Counting-sort pass 0: per-bucket edge totals (LDS-aggregated flush)
// ---------------------------------------------------------------------------
__global__ __launch_bounds__(256) void coarse_hist(
    const int* __restrict__ rows, int* __restrict__ bucketTot, int nE, int nb)
{
    __shared__ int h[MAXB];
    for (int i = threadIdx.x; i < MAXB; i += 256) h[i] = 0;
    __syncthreads();
    int stride = gridDim.x * 256;
    for (int e = blockIdx.x * 256 + threadIdx.x; e < nE; e += stride)
        atomicAdd(&h[rows[e] >> BSH], 1);
    __syncthreads();
    for (int i = threadIdx.x; i < nb; i += 256)
        if (h[i]) atomicAdd(&bucketTot[i], h[i]);
}

// ---------------------------------------------------------------------------
// Counting-sort pass 0b: exclusive scan of bucket totals (single block)
// ---------------------------------------------------------------------------
__global__ __launch_bounds__(512) void bucket_scan(
    const int* __restrict__ tot, int* __restrict__ bucketStart,
    int* __restrict__ bucketCur, int nb)
{
    int t = threadIdx.x;
    int orig = (t < nb) ? tot[t] : 0;
    int v = orig;
    int lane = t & 63, wave = t >> 6;
#pragma unroll
    for (int d = 1; d < 64; d <<= 1) {
        int u = __shfl_up(v, d);
        if (lane >= d) v += u;
    }
    __shared__ int ws[8];
    if (lane == 63) ws[wave] = v;
    __syncthreads();
    int add = 0;
    for (int w = 0; w < wave; w++) add += ws[w];
    int excl = v + add - orig;
    if (t < nb) { bucketStart[t] = excl; bucketCur[t] = excl; }
}

// ---------------------------------------------------------------------------
// Counting-sort pass 1: bucket-scatter with per-block LDS histogram + rank.
// Record: x = (rowlocal<<17) | col, y = val bits. Runs are contiguous ->
// writes L2-mergeable; tmp (25.6MB) fits aggregate L2.
// ---------------------------------------------------------------------------
__global__ __launch_bounds__(256) void pass1_scatter(
    const int* __restrict__ rows, const int* __restrict__ cols,
    const float* __restrict__ vals, int* __restrict__ bucketCur,
    uint2* __restrict__ tmp, int nE, int nb)
{
    __shared__ int hcnt[MAXB];
    __shared__ int hbase[MAXB];
    int chunk = (nE + gridDim.x - 1) / gridDim.x;
    int e0 = blockIdx.x * chunk;
    int e1 = min(e0 + chunk, nE);

    for (int i = threadIdx.x; i < MAXB; i += 256) hcnt[i] = 0;
    __syncthreads();
    for (int e = e0 + threadIdx.x; e < e1; e += 256)
        atomicAdd(&hcnt[rows[e] >> BSH], 1);
    __syncthreads();
    for (int i = threadIdx.x; i < nb; i += 256) {
        int c = hcnt[i];
        hbase[i] = c ? atomicAdd(&bucketCur[i], c) : 0;
        hcnt[i] = 0;                          // reuse as rank cursor
    }
    __syncthreads();
    for (int e = e0 + threadIdx.x; e < e1; e += 256) {  // chunk re-read is L2-hot
        int r = rows[e];
        int b = r >> BSH;
        int k = atomicAdd(&hcnt[b], 1);
        tmp[hbase[b] + k] = make_uint2(
            ((unsigned)(r & ((1 << BSH) - 1)) << 17) | (unsigned)cols[e],
            __float_as_uint(vals[e]));
    }
}

// ---------------------------------------------------------------------------
// Counting-sort pass 2: one block per bucket. LDS row-histogram + scan ->
// rowStart/rowEnd, then place final (col,val) edges. All traffic in a
// ~64KB L2-hot region.
// ---------------------------------------------------------------------------
__global__ __launch_bounds__(256) void pass2_finalize(
    const uint2* __restrict__ tmp, const int* __restrict__ bucketStart,
    const int* __restrict__ bucketCur, int* __restrict__ rowStart,
    int* __restrict__ rowEnd, int2* __restrict__ edges, int n)
{
    int b = blockIdx.x;
    int base = bucketStart[b], end = bucketCur[b];  // cur==end after pass1
    int r0 = b << BSH;
    int t = threadIdx.x;

    __shared__ int cnt[1 << BSH];
    cnt[t] = 0;
    __syncthreads();
    for (int i = base + t; i < end; i += 256)
        atomicAdd(&cnt[tmp[i].x >> 17], 1);
    __syncthreads();

    int orig = cnt[t];
    int v = orig;
    int lane = t & 63, wave = t >> 6;
#pragma unroll
    for (int d = 1; d < 64; d <<= 1) {
        int u = __shfl_up(v, d);
        if (lane >= d) v += u;
    }
    __shared__ int ws[4];
    if (lane == 63) ws[wave] = v;
    __syncthreads();
    int add = 0;
    for (int w = 0; w < wave; w++) add += ws[w];
    int offs = base + v + add - orig;               // exclusive prefix + base

    int r = r0 + t;
    if (r < n) { rowStart[r] = offs; rowEnd[r] = offs + orig; }
    cnt[t] = offs;                                  // reuse as placement cursor
    __syncthreads();
    for (int i = base + t; i < end; i += 256) {
        uint2 rec = tmp[i];
        int rl = rec.x >> 17;
        int p = atomicAdd(&cnt[rl], 1);
        edges[p] = make_int2((int)(rec.x & 0x1FFFF), (int)rec.y);
    }
}

// ---------------------------------------------------------------------------
// bf16 gather SpMM + fused Chebyshev epilogue:
//   y[row,:] = bf16( scale * sum_e val_e * x[col_e,:] + beta * prev[row,:] )
// wave64 per row; group g=lane>>4 handles edges i+g, i+4+g, i+8+g, i+12+g;
// lane l=lane&15 loads bf16x8 (16B). 16 gathers in flight per wave.
// fp32 accum; cross-group reduce via shfl_xor(16,32).
// ---------------------------------------------------------------------------
__global__ __launch_bounds__(256) void spmm_bf16(
    const int* __restrict__ rowStart, const int* __restrict__ rowEnd,
    const int2* __restrict__ edges, const unsigned short* __restrict__ xb,
    const unsigned short* __restrict__ prevb, unsigned short* __restrict__ yb,
    float scale, float beta, int n)
{
    int row = blockIdx.x * 4 + (threadIdx.x >> 6);
    if (row >= n) return;
    int lane = threadIdx.x & 63;
    int g = lane >> 4, l = lane & 15;

    int s = rowStart[row];
    int c = rowEnd[row] - s;

    float acc[8];
#pragma unroll
    for (int j = 0; j < 8; j++) acc[j] = 0.f;

    for (int i = 0; i < c; i += 16) {
        uint4 w[4];
        float v[4];
#pragma unroll
        for (int u = 0; u < 4; u++) {
            int ii = i + u * 4 + g;
            bool ok = ii < c;
            int2 e = edges[s + (ok ? ii : 0)];
            w[u] = *(const uint4*)(xb + (size_t)e.x * F + l * 8);
            v[u] = ok ? __int_as_float(e.y) : 0.f;
        }
#pragma unroll
        for (int u = 0; u < 4; u++) {
            acc[0] += v[u] * bf2f(w[u].x & 0xffffu); acc[1] += v[u] * bf2f(w[u].x >> 16);
            acc[2] += v[u] * bf2f(w[u].y & 0xffffu); acc[3] += v[u] * bf2f(w[u].y >> 16);
            acc[4] += v[u] * bf2f(w[u].z & 0xffffu); acc[5] += v[u] * bf2f(w[u].z >> 16);
            acc[6] += v[u] * bf2f(w[u].w & 0xffffu); acc[7] += v[u] * bf2f(w[u].w >> 16);
        }
    }

#pragma unroll
    for (int j = 0; j < 8; j++) {
        acc[j] += __shfl_xor(acc[j], 16);
        acc[j] += __shfl_xor(acc[j], 32);
    }

    if (g == 0) {
        float r[8];
#pragma unroll
        for (int j = 0; j < 8; j++) r[j] = scale * acc[j];
        if (beta != 0.f) {
            uint4 p = *(const uint4*)(prevb + (size_t)row * F + l * 8);
            r[0] += beta * bf2f(p.x & 0xffffu); r[1] += beta * bf2f(p.x >> 16);
            r[2] += beta * bf2f(p.y & 0xffffu); r[3] += beta * bf2f(p.y >> 16);
            r[4] += beta * bf2f(p.z & 0xffffu); r[5] += beta * bf2f(p.z >> 16);
            r[6] += beta * bf2f(p.w & 0xffffu); r[7] += beta * bf2f(p.w >> 16);
        }
        uint4 o;
        o.x = pack2(r[0], r[1]); o.y = pack2(r[2], r[3]);
        o.z = pack2(r[4], r[5]); o.w = pack2(r[6], r[7]);
        *(uint4*)(yb + (size_t)row * F + l * 8) = o;
    }
}

// ---------------------------------------------------------------------------
// out[100k,128] = cheb[100k,512](bf16 planes) @ Wp^T + bias, via MFMA 16x16x32.
// Block = 4 waves x 16 rows. B-frags straight from L2 (Wp = 128KB, hot).
// ---------------------------------------------------------------------------
__global__ __launch_bounds__(256) void gemm_mfma(
    const unsigned short* __restrict__ Tb, const unsigned short* __restrict__ Wp,
    const float* __restrict__ bias, float* __restrict__ out, int n)
{
    int wave = threadIdx.x >> 6, lane = threadIdx.x & 63;
    int l15 = lane & 15, quad = lane >> 4;
    int m0 = blockIdx.x * 64 + wave * 16;
    int m = m0 + l15;
    int mc = m < n ? m : n - 1;
    size_t planeStride = (size_t)n * F;

    floatx4 acc[8];
#pragma unroll
    for (int nt = 0; nt < 8; nt++) acc[nt] = (floatx4){0.f, 0.f, 0.f, 0.f};

    float bv[8];
#pragma unroll
    for (int nt = 0; nt < 8; nt++) bv[nt] = bias[nt * 16 + l15];

#pragma unroll
    for (int kk = 0; kk < 16; kk++) {
        const unsigned short* ap = Tb + (size_t)(kk >> 2) * planeStride
                                 + (size_t)mc * F + (kk & 3) * 32 + quad * 8;
        short8 a = __builtin_bit_cast(short8, *(const uint4*)ap);
#pragma unroll
        for (int nt = 0; nt < 8; nt++) {
            const unsigned short* bp = Wp + ((size_t)(nt * 16 + l15) << 9)
                                     + kk * 32 + quad * 8;
            short8 b = __builtin_bit_cast(short8, *(const uint4*)bp);
            acc[nt] = __builtin_amdgcn_mfma_f32_16x16x32_bf16(a, b, acc[nt], 0, 0, 0);
        }
    }

#pragma unroll
    for (int nt = 0; nt < 8; nt++) {
        int ncol = nt * 16 + l15;
#pragma unroll
        for (int r = 0; r < 4; r++) {
            int mrow = m0 + quad * 4 + r;
            if (mrow < n) out[(size_t)mrow * F + ncol] = acc[nt][r] + bv[nt];
        }
    }
}

extern "C" void kernel_launch(void* const* d_in, const int* in_sizes, int n_in,
                              void* d_out, int out_size, void* d_ws, size_t ws_size,
                              hipStream_t stream)
{
    const float* x    = (const float*)d_in[0];
    const int*   rows = (const int*)d_in[1];
    const int*   cols = (const int*)d_in[2];
    const float* vals = (const float*)d_in[3];
    const float* W    = (const float*)d_in[4];
    const float* bias = (const float*)d_in[5];

    int N = in_sizes[0] / F;
    int E = in_sizes[1];
    int NB = (N + (1 << BSH) - 1) >> BSH;       // buckets (391 for N=100k)
    float* out = (float*)d_out;

    // ---- workspace layout ----
    size_t planeElems = (size_t)N * F;                       // bf16 elems
    unsigned short* P0 = (unsigned short*)d_ws;              // 25.6 MB each
    unsigned short* P1 = P0 + planeElems;
    unsigned short* P2 = P1 + planeElems;
    unsigned short* P3 = P2 + planeElems;
    int2* edges = (int2*)(P3 + planeElems);                  // 25.6 MB
    unsigned short* Wp = (unsigned short*)(edges + E);       // 128 KB
    int* bucketTot   = (int*)(Wp + 128 * 512);               // MAXB
    int* bucketStart = bucketTot + MAXB;                     // MAXB
    int* bucketCur   = bucketStart + MAXB;                   // MAXB
    int* rowStart    = bucketCur + MAXB;                     // N
    int* rowEnd      = rowStart + N;                         // N
    uint2* tmp = (uint2*)P2;   // 25.6 MB staging, consumed before P2 written

    long long n4 = planeElems / 4;
    int castBlocks = (int)((n4 + 255) / 256);

    // ---- independent prep ----
    cast_x<<<castBlocks, 256, 0, stream>>>((const float4*)x, (uint2*)P0, n4);
    perm_w<<<256, 256, 0, stream>>>(W, Wp);

    // ---- CSR build: 2-pass counting sort, L2-resident scatter ----
    hipMemsetAsync(bucketTot, 0, MAXB * sizeof(int), stream);
    coarse_hist<<<256, 256, 0, stream>>>(rows, bucketTot, E, NB);
    bucket_scan<<<1, 512, 0, stream>>>(bucketTot, bucketStart, bucketCur, NB);
    pass1_scatter<<<512, 256, 0, stream>>>(rows, cols, vals, bucketCur, tmp, E, NB);
    pass2_finalize<<<NB, 256, 0, stream>>>(tmp, bucketStart, bucketCur,
                                           rowStart, rowEnd, edges, N);

    // ---- Chebyshev recurrence ----
    int spmmBlocks = (N + 3) / 4;
    spmm_bf16<<<spmmBlocks, 256, 0, stream>>>(rowStart, rowEnd, edges, P0, nullptr, P1, 1.0f,  0.0f, N);
    spmm_bf16<<<spmmBlocks, 256, 0, stream>>>(rowStart, rowEnd, edges, P1, P0,      P2, 2.0f, -1.0f, N);
    spmm_bf16<<<spmmBlocks, 256, 0, stream>>>(rowStart, rowEnd, edges, P2, P1,      P3, 2.0f, -1.0f, N);

    // ---- fused projection: out = cheb @ Wp^T + b ----
    gemm_mfma<<<(N + 63) / 64, 256, 0, stream>>>(P0, Wp, bias, out, N);
}

// Round 5
// 655.758 us; speedup vs baseline: 25.3868x; 1.0679x over previous
//
#include <hip/hip_runtime.h>
#include <hip/hip_bf16.h>
#include <cstdint>
#include <cstddef>

#define F 128       // feature dim
#define BSH 8       // rows per bucket = 256
#define MAXB 512    // max buckets supported (N <= 131072)
typedef __attribute__((ext_vector_type(8))) short short8;
typedef __attribute__((ext_vector_type(4))) float floatx4;

static __device__ inline float bf2f(unsigned u) {            // u = bf16 in low 16
    return __builtin_bit_cast(float, u << 16);
}
static __device__ inline unsigned short f2bf(float f) {
    return __builtin_bit_cast(unsigned short, __float2bfloat16(f));
}
static __device__ inline unsigned pack2(float a, float b) {  // low = a, high = b
    return ((unsigned)f2bf(b) << 16) | (unsigned)f2bf(a);
}

// ---------------------------------------------------------------------------
// cast x (fp32) -> plane0 (bf16). thread = 4 elements.
// ---------------------------------------------------------------------------
__global__ __launch_bounds__(256) void cast_x(
    const float4* __restrict__ x, uint2* __restrict__ p0, long long n4)
{
    long long i = (long long)blockIdx.x * 256 + threadIdx.x;
    if (i < n4) {
        float4 v = x[i];
        p0[i] = make_uint2(pack2(v.x, v.y), pack2(v.z, v.w));
    }
}

// ---------------------------------------------------------------------------
// W [128][512] fp32, W[o][f*4+j]  ->  Wp [128][512] bf16, Wp[o][j*128+f]
// ---------------------------------------------------------------------------
__global__ __launch_bounds__(256) void perm_w(
    const float* __restrict__ W, unsigned short* __restrict__ Wp)
{
    int t = blockIdx.x * 256 + threadIdx.x;   // 65536 total
    int o = t >> 9, rem = t & 511;
    int j = rem >> 7, f = rem & 127;
    Wp[t] = f2bf(W[(size_t)o * 512 + f * 4 + j]);
}

// ---------------------------------------------------------------------------
// Counting-sort pass 0: per-bucket edge totals (LDS-aggregated flush)
// ---------------------------------------------------------------------------
__global__ __launch_bounds__(256) void coarse_hist(
    const int* __restrict__ rows, int* __restrict__ bucketTot, int nE, int nb)
{
    __shared__ int h[MAXB];
    for (int i = threadIdx.x; i < MAXB; i += 256) h[i] = 0;
    __syncthreads();
    int stride = gridDim.x * 256;
    for (int e = blockIdx.x * 256 + threadIdx.x; e < nE; e += stride)
        atomicAdd(&h[rows[e] >> BSH], 1);
    __syncthreads();
    for (int i = threadIdx.x; i < nb; i += 256)
        if (h[i]) atomicAdd(&bucketTot[i], h[i]);
}

// ---------------------------------------------------------------------------
// Counting-sort pass 0b: exclusive scan of bucket totals (single block)
// ---------------------------------------------------------------------------
__global__ __launch_bounds__(512) void bucket_scan(
    const int* __restrict__ tot, int* __restrict__ bucketStart,
    int* __restrict__ bucketCur, int nb)
{
    int t = threadIdx.x;
    int orig = (t < nb) ? tot[t] : 0;
    int v = orig;
    int lane = t & 63, wave = t >> 6;
#pragma unroll
    for (int d = 1; d < 64; d <<= 1) {
        int u = __shfl_up(v, d);
        if (lane >= d) v += u;
    }
    __shared__ int ws[8];
    if (lane == 63) ws[wave] = v;
    __syncthreads();
    int add = 0;
    for (int w = 0; w < wave; w++) add += ws[w];
    int excl = v + add - orig;
    if (t < nb) { bucketStart[t] = excl; bucketCur[t] = excl; }
}

// ---------------------------------------------------------------------------
// Counting-sort pass 1: bucket-scatter with per-block LDS histogram + rank.
// ---------------------------------------------------------------------------
__global__ __launch_bounds__(256) void pass1_scatter(
    const int* __restrict__ rows, const int* __restrict__ cols,
    const float* __restrict__ vals, int* __restrict__ bucketCur,
    uint2* __restrict__ tmp, int nE, int nb)
{
    __shared__ int hcnt[MAXB];
    __shared__ int hbase[MAXB];
    int chunk = (nE + gridDim.x - 1) / gridDim.x;
    int e0 = blockIdx.x * chunk;
    int e1 = min(e0 + chunk, nE);

    for (int i = threadIdx.x; i < MAXB; i += 256) hcnt[i] = 0;
    __syncthreads();
    for (int e = e0 + threadIdx.x; e < e1; e += 256)
        atomicAdd(&hcnt[rows[e] >> BSH], 1);
    __syncthreads();
    for (int i = threadIdx.x; i < nb; i += 256) {
        int c = hcnt[i];
        hbase[i] = c ? atomicAdd(&bucketCur[i], c) : 0;
        hcnt[i] = 0;                          // reuse as rank cursor
    }
    __syncthreads();
    for (int e = e0 + threadIdx.x; e < e1; e += 256) {  // chunk re-read is L2-hot
        int r = rows[e];
        int b = r >> BSH;
        int k = atomicAdd(&hcnt[b], 1);
        tmp[hbase[b] + k] = make_uint2(
            ((unsigned)(r & ((1 << BSH) - 1)) << 17) | (unsigned)cols[e],
            __float_as_uint(vals[e]));
    }
}

// ---------------------------------------------------------------------------
// Counting-sort pass 2: one block per bucket -> rowStart/rowEnd + final edges
// ---------------------------------------------------------------------------
__global__ __launch_bounds__(256) void pass2_finalize(
    const uint2* __restrict__ tmp, const int* __restrict__ bucketStart,
    const int* __restrict__ bucketCur, int* __restrict__ rowStart,
    int* __restrict__ rowEnd, int2* __restrict__ edges, int n)
{
    int b = blockIdx.x;
    int base = bucketStart[b], end = bucketCur[b];  // cur==end after pass1
    int r0 = b << BSH;
    int t = threadIdx.x;

    __shared__ int cnt[1 << BSH];
    cnt[t] = 0;
    __syncthreads();
    for (int i = base + t; i < end; i += 256)
        atomicAdd(&cnt[tmp[i].x >> 17], 1);
    __syncthreads();

    int orig = cnt[t];
    int v = orig;
    int lane = t & 63, wave = t >> 6;
#pragma unroll
    for (int d = 1; d < 64; d <<= 1) {
        int u = __shfl_up(v, d);
        if (lane >= d) v += u;
    }
    __shared__ int ws[4];
    if (lane == 63) ws[wave] = v;
    __syncthreads();
    int add = 0;
    for (int w = 0; w < wave; w++) add += ws[w];
    int offs = base + v + add - orig;               // exclusive prefix + base

    int r = r0 + t;
    if (r < n) { rowStart[r] = offs; rowEnd[r] = offs + orig; }
    cnt[t] = offs;                                  // reuse as placement cursor
    __syncthreads();
    for (int i = base + t; i < end; i += 256) {
        uint2 rec = tmp[i];
        int rl = rec.x >> 17;
        int p = atomicAdd(&cnt[rl], 1);
        edges[p] = make_int2((int)(rec.x & 0x1FFFF), (int)rec.y);
    }
}

// ---------------------------------------------------------------------------
// bf16 gather SpMM + fused Chebyshev epilogue (unchanged from round 4)
// ---------------------------------------------------------------------------
__global__ __launch_bounds__(256) void spmm_bf16(
    const int* __restrict__ rowStart, const int* __restrict__ rowEnd,
    const int2* __restrict__ edges, const unsigned short* __restrict__ xb,
    const unsigned short* __restrict__ prevb, unsigned short* __restrict__ yb,
    float scale, float beta, int n)
{
    int row = blockIdx.x * 4 + (threadIdx.x >> 6);
    if (row >= n) return;
    int lane = threadIdx.x & 63;
    int g = lane >> 4, l = lane & 15;

    int s = rowStart[row];
    int c = rowEnd[row] - s;

    float acc[8];
#pragma unroll
    for (int j = 0; j < 8; j++) acc[j] = 0.f;

    for (int i = 0; i < c; i += 16) {
        uint4 w[4];
        float v[4];
#pragma unroll
        for (int u = 0; u < 4; u++) {
            int ii = i + u * 4 + g;
            bool ok = ii < c;
            int2 e = edges[s + (ok ? ii : 0)];
            w[u] = *(const uint4*)(xb + (size_t)e.x * F + l * 8);
            v[u] = ok ? __int_as_float(e.y) : 0.f;
        }
#pragma unroll
        for (int u = 0; u < 4; u++) {
            acc[0] += v[u] * bf2f(w[u].x & 0xffffu); acc[1] += v[u] * bf2f(w[u].x >> 16);
            acc[2] += v[u] * bf2f(w[u].y & 0xffffu); acc[3] += v[u] * bf2f(w[u].y >> 16);
            acc[4] += v[u] * bf2f(w[u].z & 0xffffu); acc[5] += v[u] * bf2f(w[u].z >> 16);
            acc[6] += v[u] * bf2f(w[u].w & 0xffffu); acc[7] += v[u] * bf2f(w[u].w >> 16);
        }
    }

#pragma unroll
    for (int j = 0; j < 8; j++) {
        acc[j] += __shfl_xor(acc[j], 16);
        acc[j] += __shfl_xor(acc[j], 32);
    }

    if (g == 0) {
        float r[8];
#pragma unroll
        for (int j = 0; j < 8; j++) r[j] = scale * acc[j];
        if (beta != 0.f) {
            uint4 p = *(const uint4*)(prevb + (size_t)row * F + l * 8);
            r[0] += beta * bf2f(p.x & 0xffffu); r[1] += beta * bf2f(p.x >> 16);
            r[2] += beta * bf2f(p.y & 0xffffu); r[3] += beta * bf2f(p.y >> 16);
            r[4] += beta * bf2f(p.z & 0xffffu); r[5] += beta * bf2f(p.z >> 16);
            r[6] += beta * bf2f(p.w & 0xffffu); r[7] += beta * bf2f(p.w >> 16);
        }
        uint4 o;
        o.x = pack2(r[0], r[1]); o.y = pack2(r[2], r[3]);
        o.z = pack2(r[4], r[5]); o.w = pack2(r[6], r[7]);
        *(uint4*)(yb + (size_t)row * F + l * 8) = o;
    }
}

// ---------------------------------------------------------------------------
// out[N,128] = cheb[N,512](bf16 planes) @ Wp^T + bias, MFMA 16x16x32.
// Register-resident B: wave w owns col-tiles nt={2w,2w+1}, preloads its 32
// B-frags (128 VGPRs) ONCE, then grid-strides over 16-row M-tiles doing
// 16 A-loads + 32 MFMAs + 8 stores per tile (vs 144 loads / 128 MFMA before).
// ---------------------------------------------------------------------------
__global__ __launch_bounds__(256) void gemm_mfma(
    const unsigned short* __restrict__ Tb, const unsigned short* __restrict__ Wp,
    const float* __restrict__ bias, float* __restrict__ out, int n, int nTiles)
{
    int wave = threadIdx.x >> 6, lane = threadIdx.x & 63;
    int l15 = lane & 15, quad = lane >> 4;
    size_t planeStride = (size_t)n * F;

    // preload B fragments for this wave's two col-tiles
    short8 bfr[2][16];
    float bv[2];
#pragma unroll
    for (int nt = 0; nt < 2; nt++) {
        int col = (wave * 2 + nt) * 16 + l15;
        bv[nt] = bias[col];
        const unsigned short* bp = Wp + ((size_t)col << 9) + quad * 8;
#pragma unroll
        for (int kk = 0; kk < 16; kk++)
            bfr[nt][kk] = __builtin_bit_cast(short8, *(const uint4*)(bp + kk * 32));
    }

    for (int tile = blockIdx.x; tile < nTiles; tile += gridDim.x) {
        int m0 = tile * 16;
        int m = m0 + l15;
        int mc = m < n ? m : n - 1;

        short8 a[16];
#pragma unroll
        for (int kk = 0; kk < 16; kk++) {
            const unsigned short* ap = Tb + (size_t)(kk >> 2) * planeStride
                                     + (size_t)mc * F + (kk & 3) * 32 + quad * 8;
            a[kk] = __builtin_bit_cast(short8, *(const uint4*)ap);
        }

        floatx4 acc[2];
        acc[0] = (floatx4){0.f, 0.f, 0.f, 0.f};
        acc[1] = (floatx4){0.f, 0.f, 0.f, 0.f};
#pragma unroll
        for (int kk = 0; kk < 16; kk++) {
            acc[0] = __builtin_amdgcn_mfma_f32_16x16x32_bf16(a[kk], bfr[0][kk], acc[0], 0, 0, 0);
            acc[1] = __builtin_amdgcn_mfma_f32_16x16x32_bf16(a[kk], bfr[1][kk], acc[1], 0, 0, 0);
        }

#pragma unroll
        for (int nt = 0; nt < 2; nt++) {
            int ncol = (wave * 2 + nt) * 16 + l15;
#pragma unroll
            for (int r = 0; r < 4; r++) {
                int mrow = m0 + quad * 4 + r;
                if (mrow < n) out[(size_t)mrow * F + ncol] = acc[nt][r] + bv[nt];
            }
        }
    }
}

extern "C" void kernel_launch(void* const* d_in, const int* in_sizes, int n_in,
                              void* d_out, int out_size, void* d_ws, size_t ws_size,
                              hipStream_t stream)
{
    const float* x    = (const float*)d_in[0];
    const int*   rows = (const int*)d_in[1];
    const int*   cols = (const int*)d_in[2];
    const float* vals = (const float*)d_in[3];
    const float* W    = (const float*)d_in[4];
    const float* bias = (const float*)d_in[5];

    int N = in_sizes[0] / F;
    int E = in_sizes[1];
    int NB = (N + (1 << BSH) - 1) >> BSH;       // buckets (391 for N=100k)
    float* out = (float*)d_out;

    // ---- workspace layout ----
    size_t planeElems = (size_t)N * F;                       // bf16 elems
    unsigned short* P0 = (unsigned short*)d_ws;              // 25.6 MB each
    unsigned short* P1 = P0 + planeElems;
    unsigned short* P2 = P1 + planeElems;
    unsigned short* P3 = P2 + planeElems;
    int2* edges = (int2*)(P3 + planeElems);                  // 25.6 MB
    unsigned short* Wp = (unsigned short*)(edges + E);       // 128 KB
    int* bucketTot   = (int*)(Wp + 128 * 512);               // MAXB
    int* bucketStart = bucketTot + MAXB;                     // MAXB
    int* bucketCur   = bucketStart + MAXB;                   // MAXB
    int* rowStart    = bucketCur + MAXB;                     // N
    int* rowEnd      = rowStart + N;                         // N
    uint2* tmp = (uint2*)P2;   // 25.6 MB staging, consumed before P2 written

    long long n4 = planeElems / 4;
    int castBlocks = (int)((n4 + 255) / 256);

    // ---- independent prep ----
    cast_x<<<castBlocks, 256, 0, stream>>>((const float4*)x, (uint2*)P0, n4);
    perm_w<<<256, 256, 0, stream>>>(W, Wp);

    // ---- CSR build: 2-pass counting sort, L2-resident scatter ----
    hipMemsetAsync(bucketTot, 0, MAXB * sizeof(int), stream);
    coarse_hist<<<256, 256, 0, stream>>>(rows, bucketTot, E, NB);
    bucket_scan<<<1, 512, 0, stream>>>(bucketTot, bucketStart, bucketCur, NB);
    pass1_scatter<<<512, 256, 0, stream>>>(rows, cols, vals, bucketCur, tmp, E, NB);
    pass2_finalize<<<NB, 256, 0, stream>>>(tmp, bucketStart, bucketCur,
                                           rowStart, rowEnd, edges, N);

    // ---- Chebyshev recurrence ----
    int spmmBlocks = (N + 3) / 4;
    spmm_bf16<<<spmmBlocks, 256, 0, stream>>>(rowStart, rowEnd, edges, P0, nullptr, P1, 1.0f,  0.0f, N);
    spmm_bf16<<<spmmBlocks, 256, 0, stream>>>(rowStart, rowEnd, edges, P1, P0,      P2, 2.0f, -1.0f, N);
    spmm_bf16<<<spmmBlocks, 256, 0, stream>>>(rowStart, rowEnd, edges, P2, P1,      P3, 2.0f, -1.0f, N);

    // ---- fused projection: out = cheb @ Wp^T + b ----
    int nTiles = (N + 15) / 16;
    int gemmGrid = nTiles < 1536 ? nTiles : 1536;
    gemm_mfma<<<gemmGrid, 256, 0, stream>>>(P0, Wp, bias, out, N, nTiles);
}